// Round 1
// baseline (669.347 us; speedup 1.0000x reference)
//
#include <hip/hip_runtime.h>
#include <hip/hip_bf16.h>
#include <math.h>

#define T_SEQ 4096
#define HIDDEN 2048
#define NH 16
#define NKV 2
#define HD 128
#define GQ (NH / NKV)
#define QKV_N ((NH + 2 * NKV) * HD)   // 2560
#define ROPE_THETA 10000.0f

using bf16 = __hip_bfloat16;
typedef __attribute__((ext_vector_type(8))) short short8;
typedef __attribute__((ext_vector_type(4))) float float4v;

// ---------------------------------------------------------------- helpers

__device__ __forceinline__ void gload_lds16(const void* g, void* l) {
  __builtin_amdgcn_global_load_lds(
      (const __attribute__((address_space(1))) unsigned int*)g,
      (__attribute__((address_space(3))) unsigned int*)l,
      16, 0, 0);
}

__device__ __forceinline__ float4v mfma_bf16(short8 a, short8 b, float4v c) {
  return __builtin_amdgcn_mfma_f32_16x16x32_bf16(a, b, c, 0, 0, 0);
}

// ---------------------------------------------------------------- f32 -> bf16

__global__ __launch_bounds__(256) void cvt_f32_bf16(const float* __restrict__ src,
                                                    bf16* __restrict__ dst, int n) {
  int i = (blockIdx.x * 256 + threadIdx.x) * 4;
  if (i + 3 < n) {
    float4 v = *reinterpret_cast<const float4*>(src + i);
    dst[i + 0] = __float2bfloat16(v.x);
    dst[i + 1] = __float2bfloat16(v.y);
    dst[i + 2] = __float2bfloat16(v.z);
    dst[i + 3] = __float2bfloat16(v.w);
  }
}

// ---------------------------------------------------------------- GEMM (C = A * B^T)
// A: [M][K] bf16 row-major, B: [N][K] bf16 row-major, C: [M][N] f32.
// 128x128 tile, BK=32, 256 threads = 4 waves (2x2 of 64x64).

__global__ __launch_bounds__(256) void gemm_bt(const bf16* __restrict__ A,
                                               const bf16* __restrict__ B,
                                               float* __restrict__ C,
                                               int N, int K) {
  const int m0 = blockIdx.y * 128;
  const int n0 = blockIdx.x * 128;
  const int tid = threadIdx.x;
  const int l = tid & 63;
  const int w = tid >> 6;
  const int lg = l >> 4;        // k-group 0..3
  const int li = l & 15;        // row/col within 16-tile
  const int wr = (w >> 1) * 64; // wave row offset in tile
  const int wc = (w & 1) * 64;  // wave col offset in tile

  __shared__ __align__(16) bf16 As[128][32];
  __shared__ __align__(16) bf16 Bs[128][32];

  float4v acc[4][4];
#pragma unroll
  for (int i = 0; i < 4; ++i)
#pragma unroll
    for (int j = 0; j < 4; ++j) acc[i][j] = (float4v)0.0f;

  // staging: wave w loads rows [w*32, w*32+32); lane l -> row w*32 + l/4, col (l%4)*8
  const int srow = w * 32 + (l >> 2);
  const int scol = (l & 3) * 8;
  const bf16* ga = A + (size_t)(m0 + srow) * K + scol;
  const bf16* gb = B + (size_t)(n0 + srow) * K + scol;
  bf16* lda = &As[0][0] + w * 1024; // wave-uniform LDS base (bytes: w*2048)
  bf16* ldb = &Bs[0][0] + w * 1024;

  for (int kt = 0; kt < K; kt += 32) {
    __syncthreads();
    gload_lds16(ga + kt, lda);
    gload_lds16(ga + (size_t)16 * K + kt, lda + 512);
    gload_lds16(gb + kt, ldb);
    gload_lds16(gb + (size_t)16 * K + kt, ldb + 512);
    __syncthreads();

    short8 a[4], b[4];
#pragma unroll
    for (int mt = 0; mt < 4; ++mt)
      a[mt] = *reinterpret_cast<const short8*>(&As[wr + mt * 16 + li][lg * 8]);
#pragma unroll
    for (int nt = 0; nt < 4; ++nt)
      b[nt] = *reinterpret_cast<const short8*>(&Bs[wc + nt * 16 + li][lg * 8]);
#pragma unroll
    for (int mt = 0; mt < 4; ++mt)
#pragma unroll
      for (int nt = 0; nt < 4; ++nt)
        acc[mt][nt] = mfma_bf16(a[mt], b[nt], acc[mt][nt]);
  }

  // C/D layout: col = lane&15, row = (lane>>4)*4 + r
#pragma unroll
  for (int mt = 0; mt < 4; ++mt) {
    const int row = m0 + wr + mt * 16 + lg * 4;
#pragma unroll
    for (int nt = 0; nt < 4; ++nt) {
      const int col = n0 + wc + nt * 16 + li;
      float* cp = C + (size_t)row * N + col;
#pragma unroll
      for (int r = 0; r < 4; ++r) cp[(size_t)r * N] = acc[mt][nt][r];
    }
  }
}

// ---------------------------------------------------------------- bias + RoPE + cast
// qkv: [T][2560] f32 raw (no bias). Writes Q [NH][T][HD], K [NKV][T][HD], V [NKV][T][HD] bf16.

__global__ __launch_bounds__(256) void rope_kernel(const float* __restrict__ qkv,
                                                   const float* __restrict__ bias,
                                                   const int* __restrict__ pos,
                                                   bf16* __restrict__ Qo,
                                                   bf16* __restrict__ Ko,
                                                   bf16* __restrict__ Vo) {
  const int t = blockIdx.x;
  const int tid = threadIdx.x;
  __shared__ float cs[64], sn[64];
  if (tid < 64) {
    float inv = powf(ROPE_THETA, -(2.0f * (float)tid) / (float)HD);
    float fr = (float)pos[t] * inv;
    float s, c;
    sincosf(fr, &s, &c);
    cs[tid] = c;
    sn[tid] = s;
  }
  __syncthreads();

  const float* row = qkv + (size_t)t * QKV_N;

  // Q: NH heads
  for (int idx = tid; idx < NH * 64; idx += 256) {
    int hh = idx >> 6, i = idx & 63;
    float x1 = row[hh * 128 + i] + bias[hh * 128 + i];
    float x2 = row[hh * 128 + 64 + i] + bias[hh * 128 + 64 + i];
    bf16* q = Qo + ((size_t)hh * T_SEQ + t) * HD;
    q[i] = __float2bfloat16(x1 * cs[i] - x2 * sn[i]);
    q[64 + i] = __float2bfloat16(x2 * cs[i] + x1 * sn[i]);
  }
  // K: NKV heads
  for (int idx = tid; idx < NKV * 64; idx += 256) {
    int hh = idx >> 6, i = idx & 63;
    float x1 = row[NH * 128 + hh * 128 + i] + bias[NH * 128 + hh * 128 + i];
    float x2 = row[NH * 128 + hh * 128 + 64 + i] + bias[NH * 128 + hh * 128 + 64 + i];
    bf16* k = Ko + ((size_t)hh * T_SEQ + t) * HD;
    k[i] = __float2bfloat16(x1 * cs[i] - x2 * sn[i]);
    k[64 + i] = __float2bfloat16(x2 * cs[i] + x1 * sn[i]);
  }
  // V: NKV heads, no rope
  for (int idx = tid; idx < NKV * HD; idx += 256) {
    int hh = idx >> 7, d = idx & 127;
    float x = row[(NH + NKV) * 128 + idx] + bias[(NH + NKV) * 128 + idx];
    Vo[((size_t)hh * T_SEQ + t) * HD + d] = __float2bfloat16(x);
  }
}

// ---------------------------------------------------------------- flash attention
// Q [NH][T][HD], K/V [NKV][T][HD] bf16 -> O [T][NH*HD] bf16. Causal, GQA.
// Block: 256 threads (4 waves), 64 q-rows (16 per wave). KV blocks of 64.

#define QB 64
#define KVB 64

__global__ __launch_bounds__(256) void attn_kernel(const bf16* __restrict__ Q,
                                                   const bf16* __restrict__ K,
                                                   const bf16* __restrict__ V,
                                                   bf16* __restrict__ O) {
  const int qb0 = blockIdx.x * QB;
  const int h = blockIdx.y;
  const int kvh = h / GQ;
  const int tid = threadIdx.x;
  const int l = tid & 63;
  const int w = tid >> 6;
  const int lg = l >> 4;
  const int li = l & 15;

  __shared__ __align__(16) bf16 Ks[KVB][HD + 8];     // 64 x 136
  __shared__ __align__(16) bf16 Vt[HD][KVB + 8];     // transposed V: 128 x 72
  __shared__ __align__(16) bf16 Pw[4][16][KVB + 8];  // per-wave P tile

  // Q fragments: A layout -> lane holds Q[row=li][kgroup(lg)*8 + e]
  short8 aq[4];
  const int qrow = qb0 + w * 16 + li;
#pragma unroll
  for (int ks = 0; ks < 4; ++ks)
    aq[ks] = *reinterpret_cast<const short8*>(
        Q + ((size_t)h * T_SEQ + qrow) * HD + ks * 32 + lg * 8);

  float4v oacc[8];
#pragma unroll
  for (int dt = 0; dt < 8; ++dt) oacc[dt] = (float4v)0.0f;
  float m_run[4], l_run[4];
#pragma unroll
  for (int r = 0; r < 4; ++r) {
    m_run[r] = -INFINITY;
    l_run[r] = 0.0f;
  }

  const float scale = 0.08838834764831845f; // 128^-0.5

  const int nkb = blockIdx.x + 1;
  for (int kb = 0; kb < nkb; ++kb) {
    const int kb0 = kb * KVB;
    __syncthreads();
    // stage K block: [64][128], coalesced, 2-way-free padded LDS
#pragma unroll
    for (int i = 0; i < 4; ++i) {
      int c = tid + i * 256;
      int row = c >> 4, col = (c & 15) * 8;
      *reinterpret_cast<short8*>(&Ks[row][col]) = *reinterpret_cast<const short8*>(
          K + ((size_t)kvh * T_SEQ + kb0 + row) * HD + col);
    }
    // stage V transposed: Vt[d][key]
#pragma unroll
    for (int i = 0; i < 16; ++i) {
      int c = tid + i * 256;
      int col = c & 127;  // d
      int rp = c >> 7;    // key pair
      ushort2 vv;
      vv.x = *reinterpret_cast<const unsigned short*>(
          V + ((size_t)kvh * T_SEQ + kb0 + 2 * rp) * HD + col);
      vv.y = *reinterpret_cast<const unsigned short*>(
          V + ((size_t)kvh * T_SEQ + kb0 + 2 * rp + 1) * HD + col);
      *reinterpret_cast<ushort2*>(&Vt[col][2 * rp]) = vv;
    }
    __syncthreads();

    // S = Q * K^T : 4 col-tiles x 4 k-slices
    float4v sacc[4];
#pragma unroll
    for (int ct = 0; ct < 4; ++ct) sacc[ct] = (float4v)0.0f;
#pragma unroll
    for (int ct = 0; ct < 4; ++ct)
#pragma unroll
      for (int ks = 0; ks < 4; ++ks) {
        short8 bk = *reinterpret_cast<const short8*>(&Ks[ct * 16 + li][ks * 32 + lg * 8]);
        sacc[ct] = mfma_bf16(aq[ks], bk, sacc[ct]);
      }

    // online softmax; S row = qb0 + w*16 + lg*4 + r, col = kb0 + ct*16 + li
#pragma unroll
    for (int r = 0; r < 4; ++r) {
      const int qg = qb0 + w * 16 + lg * 4 + r;
      float pv[4];
      float mx = -INFINITY;
#pragma unroll
      for (int ct = 0; ct < 4; ++ct) {
        float s = sacc[ct][r] * scale;
        if (kb0 + ct * 16 + li > qg) s = -INFINITY;
        pv[ct] = s;
        mx = fmaxf(mx, s);
      }
      mx = fmaxf(mx, __shfl_xor(mx, 1));
      mx = fmaxf(mx, __shfl_xor(mx, 2));
      mx = fmaxf(mx, __shfl_xor(mx, 4));
      mx = fmaxf(mx, __shfl_xor(mx, 8));
      const float mnew = fmaxf(m_run[r], mx);
      const float alpha = __expf(m_run[r] - mnew);
      m_run[r] = mnew;
      float rs = 0.0f;
#pragma unroll
      for (int ct = 0; ct < 4; ++ct) {
        float e = __expf(pv[ct] - mnew);
        rs += e;
        Pw[w][lg * 4 + r][ct * 16 + li] = __float2bfloat16(e);
      }
      rs += __shfl_xor(rs, 1);
      rs += __shfl_xor(rs, 2);
      rs += __shfl_xor(rs, 4);
      rs += __shfl_xor(rs, 8);
      l_run[r] = l_run[r] * alpha + rs;
#pragma unroll
      for (int dt = 0; dt < 8; ++dt) oacc[dt][r] *= alpha;
    }

    // drain this wave's P writes before reading them back (per-wave region, no block barrier)
    asm volatile("s_waitcnt lgkmcnt(0)" ::: "memory");

    // O += P * V : P as A-frag (row=li, k contiguous), V^T as B-frag
#pragma unroll
    for (int ks = 0; ks < 2; ++ks) {
      short8 ap = *reinterpret_cast<const short8*>(&Pw[w][li][ks * 32 + lg * 8]);
#pragma unroll
      for (int dt = 0; dt < 8; ++dt) {
        short8 bv = *reinterpret_cast<const short8*>(&Vt[dt * 16 + li][ks * 32 + lg * 8]);
        oacc[dt] = mfma_bf16(ap, bv, oacc[dt]);
      }
    }
  }

  // epilogue: O[t][h*128 + d], bf16
#pragma unroll
  for (int r = 0; r < 4; ++r) {
    const float inv = 1.0f / l_run[r];
    const int t = qb0 + w * 16 + lg * 4 + r;
    bf16* op = O + (size_t)t * (NH * HD) + h * HD;
#pragma unroll
    for (int dt = 0; dt < 8; ++dt)
      op[dt * 16 + li] = __float2bfloat16(oacc[dt][r] * inv);
  }
}

// ---------------------------------------------------------------- launch

extern "C" void kernel_launch(void* const* d_in, const int* in_sizes, int n_in,
                              void* d_out, int out_size, void* d_ws, size_t ws_size,
                              hipStream_t stream) {
  const int* positions = (const int*)d_in[0];
  const float* hidden = (const float*)d_in[1];
  const float* w_qkv = (const float*)d_in[2];
  const float* b_qkv = (const float*)d_in[3];
  const float* w_o = (const float*)d_in[4];
  float* out = (float*)d_out;

  char* ws = (char*)d_ws;
  bf16* hs_bf = (bf16*)ws;   ws += (size_t)T_SEQ * HIDDEN * 2;
  bf16* wqkv_bf = (bf16*)ws; ws += (size_t)QKV_N * HIDDEN * 2;
  bf16* wo_bf = (bf16*)ws;   ws += (size_t)HIDDEN * HIDDEN * 2;
  float* qkv_f = (float*)ws; ws += (size_t)T_SEQ * QKV_N * 4;
  bf16* q_bf = (bf16*)ws;    ws += (size_t)NH * T_SEQ * HD * 2;
  bf16* k_bf = (bf16*)ws;    ws += (size_t)NKV * T_SEQ * HD * 2;
  bf16* v_bf = (bf16*)ws;    ws += (size_t)NKV * T_SEQ * HD * 2;
  bf16* attn_bf = (bf16*)ws; ws += (size_t)T_SEQ * HIDDEN * 2;

  cvt_f32_bf16<<<(T_SEQ * HIDDEN) / 1024, 256, 0, stream>>>(hidden, hs_bf, T_SEQ * HIDDEN);
  cvt_f32_bf16<<<(QKV_N * HIDDEN) / 1024, 256, 0, stream>>>(w_qkv, wqkv_bf, QKV_N * HIDDEN);
  cvt_f32_bf16<<<(HIDDEN * HIDDEN) / 1024, 256, 0, stream>>>(w_o, wo_bf, HIDDEN * HIDDEN);

  gemm_bt<<<dim3(QKV_N / 128, T_SEQ / 128), 256, 0, stream>>>(hs_bf, wqkv_bf, qkv_f,
                                                              QKV_N, HIDDEN);

  rope_kernel<<<T_SEQ, 256, 0, stream>>>(qkv_f, b_qkv, positions, q_bf, k_bf, v_bf);

  attn_kernel<<<dim3(T_SEQ / QB, NH), 256, 0, stream>>>(q_bf, k_bf, v_bf, attn_bf);

  gemm_bt<<<dim3(HIDDEN / 128, T_SEQ / 128), 256, 0, stream>>>(attn_bf, wo_bf, out,
                                                               HIDDEN, HIDDEN);
}

// Round 2
// 588.605 us; speedup vs baseline: 1.1372x; 1.1372x over previous
//
#include <hip/hip_runtime.h>
#include <hip/hip_bf16.h>
#include <math.h>

#define T_SEQ 4096
#define HIDDEN 2048
#define NH 16
#define NKV 2
#define HD 128
#define GQ (NH / NKV)
#define QKV_N 2560
#define ROPE_THETA 10000.0f

using bf16 = __hip_bfloat16;
typedef __attribute__((ext_vector_type(8))) short short8;
typedef __attribute__((ext_vector_type(4))) float float4v;

// ---------------------------------------------------------------- helpers

__device__ __forceinline__ void gload_lds16(const void* g, void* l) {
  __builtin_amdgcn_global_load_lds(
      (const __attribute__((address_space(1))) unsigned int*)g,
      (__attribute__((address_space(3))) unsigned int*)l,
      16, 0, 0);
}

__device__ __forceinline__ float4v mfma_bf16(short8 a, short8 b, float4v c) {
  return __builtin_amdgcn_mfma_f32_16x16x32_bf16(a, b, c, 0, 0, 0);
}

// ---------------------------------------------------------------- f32 -> bf16

__global__ __launch_bounds__(256) void cvt_f32_bf16(const float* __restrict__ src,
                                                    bf16* __restrict__ dst, int n) {
  int i = (blockIdx.x * 256 + threadIdx.x) * 4;
  if (i + 3 < n) {
    float4 v = *reinterpret_cast<const float4*>(src + i);
    dst[i + 0] = __float2bfloat16(v.x);
    dst[i + 1] = __float2bfloat16(v.y);
    dst[i + 2] = __float2bfloat16(v.z);
    dst[i + 3] = __float2bfloat16(v.w);
  }
}

// ---------------------------------------------------------------- GEMM (C = A * B^T)
// A: [M][K] bf16 row-major, B: [N][K] bf16 row-major, C: [M][N] f32.
// 128x128 tile, BK=64, 4 waves (2x2 of 64x64), XOR-swizzled LDS (16B blocks),
// staged via global_load_lds with pre-swizzled global source addresses.

__global__ __launch_bounds__(256) void gemm_bt(const bf16* __restrict__ A,
                                               const bf16* __restrict__ B,
                                               float* __restrict__ C,
                                               int N, int K) {
  const int m0 = blockIdx.y * 128;
  const int n0 = blockIdx.x * 128;
  const int tid = threadIdx.x;
  const int l = tid & 63;
  const int w = tid >> 6;
  const int lg = l >> 4;
  const int li = l & 15;
  const int wr = (w >> 1) * 64;
  const int wc = (w & 1) * 64;

  __shared__ __align__(16) bf16 As[128][64];
  __shared__ __align__(16) bf16 Bs[128][64];

  float4v acc[4][4];
#pragma unroll
  for (int i = 0; i < 4; ++i)
#pragma unroll
    for (int j = 0; j < 4; ++j) acc[i][j] = (float4v)0.0f;

  // staging: wave w owns rows [w*32, w*32+32). instr j covers rows w*32+j*8+(l>>3).
  // LDS is row-linear; the col-block swizzle (cb ^ (row&7)) is applied on the
  // GLOBAL source address (row&7 == (l>>3)&7, j-independent since j*8 % 8 == 0).
  const int srow = w * 32 + (l >> 3);
  const int scol = ((l & 7) ^ ((l >> 3) & 7)) * 8;
  const bf16* ga = A + (size_t)(m0 + srow) * K + scol;
  const bf16* gb = B + (size_t)(n0 + srow) * K + scol;
  bf16* la = &As[0][0] + w * 2048;
  bf16* lb = &Bs[0][0] + w * 2048;

  for (int kt = 0; kt < K; kt += 64) {
    __syncthreads();
#pragma unroll
    for (int j = 0; j < 4; ++j) {
      gload_lds16(ga + (size_t)j * 8 * K + kt, la + j * 512);
      gload_lds16(gb + (size_t)j * 8 * K + kt, lb + j * 512);
    }
    __syncthreads();

#pragma unroll
    for (int ks = 0; ks < 2; ++ks) {
      short8 a[4], b[4];
#pragma unroll
      for (int mt = 0; mt < 4; ++mt)
        a[mt] = *reinterpret_cast<const short8*>(
            &As[wr + mt * 16 + li][((ks * 4 + lg) ^ (li & 7)) * 8]);
#pragma unroll
      for (int nt = 0; nt < 4; ++nt)
        b[nt] = *reinterpret_cast<const short8*>(
            &Bs[wc + nt * 16 + li][((ks * 4 + lg) ^ (li & 7)) * 8]);
#pragma unroll
      for (int mt = 0; mt < 4; ++mt)
#pragma unroll
        for (int nt = 0; nt < 4; ++nt)
          acc[mt][nt] = mfma_bf16(a[mt], b[nt], acc[mt][nt]);
    }
  }

  // C/D layout: col = lane&15, row = (lane>>4)*4 + r
#pragma unroll
  for (int mt = 0; mt < 4; ++mt) {
    const int row = m0 + wr + mt * 16 + lg * 4;
#pragma unroll
    for (int nt = 0; nt < 4; ++nt) {
      const int col = n0 + wc + nt * 16 + li;
      float* cp = C + (size_t)row * N + col;
#pragma unroll
      for (int r = 0; r < 4; ++r) cp[(size_t)r * N] = acc[mt][nt][r];
    }
  }
}

// ---------------------------------------------------------------- bias + RoPE + cast
// qkv: [T][2560] f32 raw. Writes Q [NH][T][HD], K [NKV][T][HD], V^T [NKV][HD][T] bf16.

__global__ __launch_bounds__(256) void rope_kernel(const float* __restrict__ qkv,
                                                   const float* __restrict__ bias,
                                                   const int* __restrict__ pos,
                                                   bf16* __restrict__ Qo,
                                                   bf16* __restrict__ Ko,
                                                   bf16* __restrict__ Vto) {
  const int t = blockIdx.x;
  const int tid = threadIdx.x;
  __shared__ float cs[64], sn[64];
  if (tid < 64) {
    float inv = powf(ROPE_THETA, -(2.0f * (float)tid) / (float)HD);
    float fr = (float)pos[t] * inv;
    float s, c;
    sincosf(fr, &s, &c);
    cs[tid] = c;
    sn[tid] = s;
  }
  __syncthreads();

  const float* row = qkv + (size_t)t * QKV_N;

  for (int idx = tid; idx < NH * 64; idx += 256) {
    int hh = idx >> 6, i = idx & 63;
    float x1 = row[hh * 128 + i] + bias[hh * 128 + i];
    float x2 = row[hh * 128 + 64 + i] + bias[hh * 128 + 64 + i];
    bf16* q = Qo + ((size_t)hh * T_SEQ + t) * HD;
    q[i] = __float2bfloat16(x1 * cs[i] - x2 * sn[i]);
    q[64 + i] = __float2bfloat16(x2 * cs[i] + x1 * sn[i]);
  }
  for (int idx = tid; idx < NKV * 64; idx += 256) {
    int hh = idx >> 6, i = idx & 63;
    float x1 = row[NH * 128 + hh * 128 + i] + bias[NH * 128 + hh * 128 + i];
    float x2 = row[NH * 128 + hh * 128 + 64 + i] + bias[NH * 128 + hh * 128 + 64 + i];
    bf16* k = Ko + ((size_t)hh * T_SEQ + t) * HD;
    k[i] = __float2bfloat16(x1 * cs[i] - x2 * sn[i]);
    k[64 + i] = __float2bfloat16(x2 * cs[i] + x1 * sn[i]);
  }
  // V transposed: Vto[kvh][d][t]
  for (int idx = tid; idx < NKV * HD; idx += 256) {
    int hh = idx >> 7, d = idx & 127;
    float x = row[(NH + NKV) * 128 + idx] + bias[(NH + NKV) * 128 + idx];
    Vto[((size_t)hh * HD + d) * T_SEQ + t] = __float2bfloat16(x);
  }
}

// ---------------------------------------------------------------- flash attention
// Q [NH][T][HD], K [NKV][T][HD], V^T [NKV][HD][T] bf16 -> O [T][NH*HD] bf16.
// 4 waves x 16 q-rows, KVB=64. K/V staged linearly via global_load_lds with
// pre-swizzled global sources; all LDS column reads XOR-swizzled (conflict-free).

#define QB 64
#define KVB 64

__global__ __launch_bounds__(256) void attn_kernel(const bf16* __restrict__ Q,
                                                   const bf16* __restrict__ K,
                                                   const bf16* __restrict__ Vt_g,
                                                   bf16* __restrict__ O) {
  const int qi = (int)gridDim.x - 1 - (int)blockIdx.x;  // heavy blocks first
  const int qb0 = qi * QB;
  const int h = blockIdx.y;
  const int kvh = h / GQ;
  const int tid = threadIdx.x;
  const int l = tid & 63;
  const int w = tid >> 6;
  const int lg = l >> 4;
  const int li = l & 15;

  __shared__ __align__(16) bf16 Ks[KVB][HD];     // keys x d, swizzled storage
  __shared__ __align__(16) bf16 Vs[HD][KVB];     // d x keys (V^T), swizzled
  __shared__ __align__(16) bf16 Pw[4][16][KVB];  // per-wave P, swizzled

  // Q A-fragments: lane = row li, k = ks*32 + lg*8
  short8 aq[4];
  const int qrow = qb0 + w * 16 + li;
#pragma unroll
  for (int ks = 0; ks < 4; ++ks)
    aq[ks] = *reinterpret_cast<const short8*>(
        Q + ((size_t)h * T_SEQ + qrow) * HD + ks * 32 + lg * 8);

  // K staging: wave w rows w*16 + j*4 + (l>>4); swizzled col block (l&15)^(r&7),
  // r&7 = (j&1)*4 + (l>>4). Two base pointers (j even / j odd).
  const bf16* gke = K + ((size_t)kvh * T_SEQ + w * 16 + (l >> 4)) * HD +
                    (((l & 15) ^ (l >> 4)) * 8);
  const bf16* gko = K + ((size_t)kvh * T_SEQ + w * 16 + (l >> 4)) * HD +
                    (((l & 15) ^ (4 + (l >> 4))) * 8);
  // V staging: wave w rows (d) w*32 + j*8 + (l>>3); r&7 = (l>>3)&7, j-independent.
  const bf16* gv = Vt_g + ((size_t)kvh * HD + w * 32 + (l >> 3)) * T_SEQ +
                   (((l & 7) ^ ((l >> 3) & 7)) * 8);
  bf16* lk = &Ks[0][0] + w * 2048;
  bf16* lv = &Vs[0][0] + w * 2048;

  float4v oacc[8];
#pragma unroll
  for (int dt = 0; dt < 8; ++dt) oacc[dt] = (float4v)0.0f;
  float m_run[4], l_run[4];
#pragma unroll
  for (int r = 0; r < 4; ++r) {
    m_run[r] = -INFINITY;
    l_run[r] = 0.0f;
  }

  const float scl2 = 0.08838834764831845f * 1.4426950408889634f;  // 128^-.5 * log2e

  const int nkb = qi + 1;
  for (int kb = 0; kb < nkb; ++kb) {
    const int kb0 = kb * KVB;
    __syncthreads();
#pragma unroll
    for (int j = 0; j < 4; ++j) {
      const bf16* gkj = ((j & 1) ? gko : gke) + (size_t)(kb0 + j * 4) * HD;
      gload_lds16(gkj, lk + j * 512);
      gload_lds16(gv + (size_t)j * 8 * T_SEQ + kb0, lv + j * 512);
    }
    __syncthreads();

    // S = Q K^T (base-2-scaled). B-frag: lane col = key = ct*16+li, k contiguous.
    float4v sacc[4];
#pragma unroll
    for (int ct = 0; ct < 4; ++ct) sacc[ct] = (float4v)0.0f;
#pragma unroll
    for (int ct = 0; ct < 4; ++ct)
#pragma unroll
      for (int ks = 0; ks < 4; ++ks) {
        short8 bk = *reinterpret_cast<const short8*>(
            &Ks[ct * 16 + li][((ks * 4 + lg) ^ (li & 7)) * 8]);
        sacc[ct] = mfma_bf16(aq[ks], bk, sacc[ct]);
      }

    const bool diag = (kb == nkb - 1);
#pragma unroll
    for (int r = 0; r < 4; ++r) {
      float pv[4];
      if (diag) {
        const int qg = qb0 + w * 16 + lg * 4 + r;
#pragma unroll
        for (int ct = 0; ct < 4; ++ct) {
          float s = sacc[ct][r] * scl2;
          if (kb0 + ct * 16 + li > qg) s = -INFINITY;
          pv[ct] = s;
        }
      } else {
#pragma unroll
        for (int ct = 0; ct < 4; ++ct) pv[ct] = sacc[ct][r] * scl2;
      }
      float mx = fmaxf(fmaxf(pv[0], pv[1]), fmaxf(pv[2], pv[3]));
      mx = fmaxf(mx, __shfl_xor(mx, 1));
      mx = fmaxf(mx, __shfl_xor(mx, 2));
      mx = fmaxf(mx, __shfl_xor(mx, 4));
      mx = fmaxf(mx, __shfl_xor(mx, 8));
      const float mnew = fmaxf(m_run[r], mx);
      const float alpha = exp2f(m_run[r] - mnew);
      m_run[r] = mnew;
      const int prow = lg * 4 + r;
      float rs = 0.0f;
#pragma unroll
      for (int ct = 0; ct < 4; ++ct) {
        float e = exp2f(pv[ct] - mnew);
        rs += e;
        Pw[w][prow][(ct * 16 + li) ^ ((prow & 7) << 3)] = __float2bfloat16(e);
      }
      rs += __shfl_xor(rs, 1);
      rs += __shfl_xor(rs, 2);
      rs += __shfl_xor(rs, 4);
      rs += __shfl_xor(rs, 8);
      l_run[r] = l_run[r] * alpha + rs;
#pragma unroll
      for (int dt = 0; dt < 8; ++dt) oacc[dt][r] *= alpha;
    }

    // drain this wave's P writes before reading them back (per-wave buffer)
    asm volatile("s_waitcnt lgkmcnt(0)" ::: "memory");
    __builtin_amdgcn_sched_barrier(0);

    // O += P V : A-frag = P (row li, k contig), B-frag = V^T (col li = d, k contig)
#pragma unroll
    for (int ks = 0; ks < 2; ++ks) {
      short8 ap = *reinterpret_cast<const short8*>(
          &Pw[w][li][((ks * 4 + lg) ^ (li & 7)) * 8]);
#pragma unroll
      for (int dt = 0; dt < 8; ++dt) {
        short8 bv = *reinterpret_cast<const short8*>(
            &Vs[dt * 16 + li][((ks * 4 + lg) ^ (li & 7)) * 8]);
        oacc[dt] = mfma_bf16(ap, bv, oacc[dt]);
      }
    }
  }

  // epilogue: O[t][h*128 + d]
#pragma unroll
  for (int r = 0; r < 4; ++r) {
    const float inv = 1.0f / l_run[r];
    const int t = qb0 + w * 16 + lg * 4 + r;
    bf16* op = O + (size_t)t * (NH * HD) + h * HD;
#pragma unroll
    for (int dt = 0; dt < 8; ++dt)
      op[dt * 16 + li] = __float2bfloat16(oacc[dt][r] * inv);
  }
}

// ---------------------------------------------------------------- launch

extern "C" void kernel_launch(void* const* d_in, const int* in_sizes, int n_in,
                              void* d_out, int out_size, void* d_ws, size_t ws_size,
                              hipStream_t stream) {
  const int* positions = (const int*)d_in[0];
  const float* hidden = (const float*)d_in[1];
  const float* w_qkv = (const float*)d_in[2];
  const float* b_qkv = (const float*)d_in[3];
  const float* w_o = (const float*)d_in[4];
  float* out = (float*)d_out;

  char* ws = (char*)d_ws;
  bf16* hs_bf = (bf16*)ws;   ws += (size_t)T_SEQ * HIDDEN * 2;
  bf16* wqkv_bf = (bf16*)ws; ws += (size_t)QKV_N * HIDDEN * 2;
  bf16* wo_bf = (bf16*)ws;   ws += (size_t)HIDDEN * HIDDEN * 2;
  float* qkv_f = (float*)ws; ws += (size_t)T_SEQ * QKV_N * 4;
  bf16* q_bf = (bf16*)ws;    ws += (size_t)NH * T_SEQ * HD * 2;
  bf16* k_bf = (bf16*)ws;    ws += (size_t)NKV * T_SEQ * HD * 2;
  bf16* vt_bf = (bf16*)ws;   ws += (size_t)NKV * T_SEQ * HD * 2;
  bf16* attn_bf = (bf16*)ws; ws += (size_t)T_SEQ * HIDDEN * 2;

  cvt_f32_bf16<<<(T_SEQ * HIDDEN) / 1024, 256, 0, stream>>>(hidden, hs_bf, T_SEQ * HIDDEN);
  cvt_f32_bf16<<<(QKV_N * HIDDEN) / 1024, 256, 0, stream>>>(w_qkv, wqkv_bf, QKV_N * HIDDEN);
  cvt_f32_bf16<<<(HIDDEN * HIDDEN) / 1024, 256, 0, stream>>>(w_o, wo_bf, HIDDEN * HIDDEN);

  gemm_bt<<<dim3(QKV_N / 128, T_SEQ / 128), 256, 0, stream>>>(hs_bf, wqkv_bf, qkv_f,
                                                              QKV_N, HIDDEN);

  rope_kernel<<<T_SEQ, 256, 0, stream>>>(qkv_f, b_qkv, positions, q_bf, k_bf, vt_bf);

  attn_kernel<<<dim3(T_SEQ / QB, NH), 256, 0, stream>>>(q_bf, k_bf, vt_bf, attn_bf);

  gemm_bt<<<dim3(HIDDEN / 128, T_SEQ / 128), 256, 0, stream>>>(attn_bf, wo_bf, out,
                                                               HIDDEN, HIDDEN);
}

// Round 3
// 496.694 us; speedup vs baseline: 1.3476x; 1.1850x over previous
//
#include <hip/hip_runtime.h>
#include <hip/hip_bf16.h>
#include <math.h>

#define T_SEQ 4096
#define HIDDEN 2048
#define NH 16
#define NKV 2
#define HD 128
#define GQ (NH / NKV)
#define QKV_N 2560
#define ROPE_THETA 10000.0f

using bf16 = __hip_bfloat16;
typedef __attribute__((ext_vector_type(8))) short short8;
typedef __attribute__((ext_vector_type(4))) float float4v;

// ---------------------------------------------------------------- helpers

__device__ __forceinline__ void gload_lds16(const void* g, void* l) {
  __builtin_amdgcn_global_load_lds(
      (const __attribute__((address_space(1))) unsigned int*)g,
      (__attribute__((address_space(3))) unsigned int*)l,
      16, 0, 0);
}

__device__ __forceinline__ float4v mfma_bf16(short8 a, short8 b, float4v c) {
  return __builtin_amdgcn_mfma_f32_16x16x32_bf16(a, b, c, 0, 0, 0);
}

// ---------------------------------------------------------------- f32 -> bf16

__global__ __launch_bounds__(256) void cvt_f32_bf16(const float* __restrict__ src,
                                                    bf16* __restrict__ dst, int n) {
  int i = (blockIdx.x * 256 + threadIdx.x) * 4;
  if (i + 3 < n) {
    float4 v = *reinterpret_cast<const float4*>(src + i);
    dst[i + 0] = __float2bfloat16(v.x);
    dst[i + 1] = __float2bfloat16(v.y);
    dst[i + 2] = __float2bfloat16(v.z);
    dst[i + 3] = __float2bfloat16(v.w);
  }
}

// ---------------------------------------------------------------- GEMM (C = A * B^T)
// 128x128 tile, BK=64, 4 waves (2x2 of 64x64), XOR-swizzled LDS, global_load_lds.

__global__ __launch_bounds__(256) void gemm_bt(const bf16* __restrict__ A,
                                               const bf16* __restrict__ B,
                                               float* __restrict__ C,
                                               int N, int K) {
  const int m0 = blockIdx.y * 128;
  const int n0 = blockIdx.x * 128;
  const int tid = threadIdx.x;
  const int l = tid & 63;
  const int w = tid >> 6;
  const int lg = l >> 4;
  const int li = l & 15;
  const int wr = (w >> 1) * 64;
  const int wc = (w & 1) * 64;

  __shared__ __align__(16) bf16 As[128][64];
  __shared__ __align__(16) bf16 Bs[128][64];

  float4v acc[4][4];
#pragma unroll
  for (int i = 0; i < 4; ++i)
#pragma unroll
    for (int j = 0; j < 4; ++j) acc[i][j] = (float4v)0.0f;

  const int srow = w * 32 + (l >> 3);
  const int scol = ((l & 7) ^ ((l >> 3) & 7)) * 8;
  const bf16* ga = A + (size_t)(m0 + srow) * K + scol;
  const bf16* gb = B + (size_t)(n0 + srow) * K + scol;
  bf16* la = &As[0][0] + w * 2048;
  bf16* lb = &Bs[0][0] + w * 2048;

  for (int kt = 0; kt < K; kt += 64) {
    __syncthreads();
#pragma unroll
    for (int j = 0; j < 4; ++j) {
      gload_lds16(ga + (size_t)j * 8 * K + kt, la + j * 512);
      gload_lds16(gb + (size_t)j * 8 * K + kt, lb + j * 512);
    }
    __syncthreads();

#pragma unroll
    for (int ks = 0; ks < 2; ++ks) {
      short8 a[4], b[4];
#pragma unroll
      for (int mt = 0; mt < 4; ++mt)
        a[mt] = *reinterpret_cast<const short8*>(
            &As[wr + mt * 16 + li][((ks * 4 + lg) ^ (li & 7)) * 8]);
#pragma unroll
      for (int nt = 0; nt < 4; ++nt)
        b[nt] = *reinterpret_cast<const short8*>(
            &Bs[wc + nt * 16 + li][((ks * 4 + lg) ^ (li & 7)) * 8]);
#pragma unroll
      for (int mt = 0; mt < 4; ++mt)
#pragma unroll
        for (int nt = 0; nt < 4; ++nt)
          acc[mt][nt] = mfma_bf16(a[mt], b[nt], acc[mt][nt]);
    }
  }

#pragma unroll
  for (int mt = 0; mt < 4; ++mt) {
    const int row = m0 + wr + mt * 16 + lg * 4;
#pragma unroll
    for (int nt = 0; nt < 4; ++nt) {
      const int col = n0 + wc + nt * 16 + li;
      float* cp = C + (size_t)row * N + col;
#pragma unroll
      for (int r = 0; r < 4; ++r) cp[(size_t)r * N] = acc[mt][nt][r];
    }
  }
}

// ---------------------------------------------------------------- bias + RoPE + cast
// Q is pre-scaled by HD^-0.5 * log2(e) (softmax done in base-2 domain).

#define QSCALE 0.12753588594439120f  // 128^-0.5 * log2(e)

__global__ __launch_bounds__(256) void rope_kernel(const float* __restrict__ qkv,
                                                   const float* __restrict__ bias,
                                                   const int* __restrict__ pos,
                                                   bf16* __restrict__ Qo,
                                                   bf16* __restrict__ Ko,
                                                   bf16* __restrict__ Vto) {
  const int t = blockIdx.x;
  const int tid = threadIdx.x;
  __shared__ float cs[64], sn[64];
  if (tid < 64) {
    float inv = powf(ROPE_THETA, -(2.0f * (float)tid) / (float)HD);
    float fr = (float)pos[t] * inv;
    float s, c;
    sincosf(fr, &s, &c);
    cs[tid] = c;
    sn[tid] = s;
  }
  __syncthreads();

  const float* row = qkv + (size_t)t * QKV_N;

  for (int idx = tid; idx < NH * 64; idx += 256) {
    int hh = idx >> 6, i = idx & 63;
    float x1 = row[hh * 128 + i] + bias[hh * 128 + i];
    float x2 = row[hh * 128 + 64 + i] + bias[hh * 128 + 64 + i];
    bf16* q = Qo + ((size_t)hh * T_SEQ + t) * HD;
    q[i] = __float2bfloat16((x1 * cs[i] - x2 * sn[i]) * QSCALE);
    q[64 + i] = __float2bfloat16((x2 * cs[i] + x1 * sn[i]) * QSCALE);
  }
  for (int idx = tid; idx < NKV * 64; idx += 256) {
    int hh = idx >> 6, i = idx & 63;
    float x1 = row[NH * 128 + hh * 128 + i] + bias[NH * 128 + hh * 128 + i];
    float x2 = row[NH * 128 + hh * 128 + 64 + i] + bias[NH * 128 + hh * 128 + 64 + i];
    bf16* k = Ko + ((size_t)hh * T_SEQ + t) * HD;
    k[i] = __float2bfloat16(x1 * cs[i] - x2 * sn[i]);
    k[64 + i] = __float2bfloat16(x2 * cs[i] + x1 * sn[i]);
  }
  for (int idx = tid; idx < NKV * HD; idx += 256) {
    int hh = idx >> 7, d = idx & 127;
    float x = row[(NH + NKV) * 128 + idx] + bias[(NH + NKV) * 128 + idx];
    Vto[((size_t)hh * HD + d) * T_SEQ + t] = __float2bfloat16(x);
  }
}

// ---------------------------------------------------------------- flash attention
// Double-buffered K/V (async prefetch, one barrier/iter), defer-max softmax,
// deferred denominator reduce. Q pre-scaled; softmax in base-2.

#define QB 64
#define KVB 64
#define DEFER_THR 8.0f

__global__ __launch_bounds__(256) void attn_kernel(const bf16* __restrict__ Q,
                                                   const bf16* __restrict__ K,
                                                   const bf16* __restrict__ Vt_g,
                                                   bf16* __restrict__ O) {
  const int qi = (int)gridDim.x - 1 - (int)blockIdx.x;  // heavy blocks first
  const int qb0 = qi * QB;
  const int h = blockIdx.y;
  const int kvh = h / GQ;
  const int tid = threadIdx.x;
  const int l = tid & 63;
  const int w = tid >> 6;
  const int lg = l >> 4;
  const int li = l & 15;

  __shared__ __align__(16) bf16 Ks[2][KVB][HD];   // 32 KB
  __shared__ __align__(16) bf16 Vs[2][HD][KVB];   // 32 KB
  __shared__ __align__(16) bf16 Pw[4][16][KVB];   // 8 KB

  // staging base addresses (pre-swizzled global sources, linear LDS dest)
  const bf16* gke = K + ((size_t)kvh * T_SEQ + w * 16 + (l >> 4)) * HD +
                    (((l & 15) ^ (l >> 4)) * 8);
  const bf16* gko = K + ((size_t)kvh * T_SEQ + w * 16 + (l >> 4)) * HD +
                    (((l & 15) ^ (4 + (l >> 4))) * 8);
  const bf16* gv = Vt_g + ((size_t)kvh * HD + w * 32 + (l >> 3)) * T_SEQ +
                   (((l & 7) ^ ((l >> 3) & 7)) * 8);
  bf16* lk = &Ks[0][0][0] + w * 2048;
  bf16* lv = &Vs[0][0][0] + w * 2048;

  const int nkb = qi + 1;

  // prologue: stage kb=0 into buffer 0
#pragma unroll
  for (int j = 0; j < 4; ++j) {
    const bf16* gkj = ((j & 1) ? gko : gke) + (size_t)(j * 4) * HD;
    gload_lds16(gkj, lk + j * 512);
    gload_lds16(gv + (size_t)j * 8 * T_SEQ, lv + j * 512);
  }

  // Q A-fragments (already scaled by QSCALE)
  short8 aq[4];
  const int qrow = qb0 + w * 16 + li;
#pragma unroll
  for (int ks = 0; ks < 4; ++ks)
    aq[ks] = *reinterpret_cast<const short8*>(
        Q + ((size_t)h * T_SEQ + qrow) * HD + ks * 32 + lg * 8);

  float4v oacc[8];
#pragma unroll
  for (int dt = 0; dt < 8; ++dt) oacc[dt] = (float4v)0.0f;
  float m_run[4], l_part[4];
#pragma unroll
  for (int r = 0; r < 4; ++r) {
    m_run[r] = -INFINITY;
    l_part[r] = 0.0f;
  }

  asm volatile("s_waitcnt vmcnt(0)" ::: "memory");
  __syncthreads();

  for (int kb = 0; kb < nkb; ++kb) {
    const int cur = kb & 1;
    const int nxt = cur ^ 1;

    // async prefetch of next K/V tile into the other buffer
    if (kb + 1 < nkb) {
      const int kb0n = (kb + 1) * KVB;
#pragma unroll
      for (int j = 0; j < 4; ++j) {
        const bf16* gkj = ((j & 1) ? gko : gke) + (size_t)(kb0n + j * 4) * HD;
        gload_lds16(gkj, lk + nxt * 8192 + j * 512);
        gload_lds16(gv + (size_t)j * 8 * T_SEQ + kb0n, lv + nxt * 8192 + j * 512);
      }
    }

    // S = Q K^T (base-2-scaled; Q pre-scaled)
    float4v sacc[4];
#pragma unroll
    for (int ct = 0; ct < 4; ++ct) sacc[ct] = (float4v)0.0f;
#pragma unroll
    for (int ct = 0; ct < 4; ++ct)
#pragma unroll
      for (int ks = 0; ks < 4; ++ks) {
        short8 bk = *reinterpret_cast<const short8*>(
            &Ks[cur][ct * 16 + li][((ks * 4 + lg) ^ (li & 7)) * 8]);
        sacc[ct] = mfma_bf16(aq[ks], bk, sacc[ct]);
      }

    // causal mask on the diagonal tile only
    if (kb == nkb - 1) {
      const int kb0 = kb * KVB;
#pragma unroll
      for (int ct = 0; ct < 4; ++ct) {
        const int col = kb0 + ct * 16 + li;
#pragma unroll
        for (int r = 0; r < 4; ++r)
          if (col > qb0 + w * 16 + lg * 4 + r) sacc[ct][r] = -INFINITY;
      }
    }

    // defer-max online softmax
    bool need = false;
#pragma unroll
    for (int r = 0; r < 4; ++r) {
      const float thr = m_run[r] + DEFER_THR;
#pragma unroll
      for (int ct = 0; ct < 4; ++ct) need |= (sacc[ct][r] > thr);
    }
    if (__any(need)) {
#pragma unroll
      for (int r = 0; r < 4; ++r) {
        float mx = fmaxf(fmaxf(sacc[0][r], sacc[1][r]), fmaxf(sacc[2][r], sacc[3][r]));
        mx = fmaxf(mx, __shfl_xor(mx, 1));
        mx = fmaxf(mx, __shfl_xor(mx, 2));
        mx = fmaxf(mx, __shfl_xor(mx, 4));
        mx = fmaxf(mx, __shfl_xor(mx, 8));
        const float mnew = fmaxf(m_run[r], mx);
        const float alpha = exp2f(m_run[r] - mnew);
        m_run[r] = mnew;
        l_part[r] *= alpha;
#pragma unroll
        for (int dt = 0; dt < 8; ++dt) oacc[dt][r] *= alpha;
      }
    }
#pragma unroll
    for (int r = 0; r < 4; ++r) {
      const int prow = lg * 4 + r;
#pragma unroll
      for (int ct = 0; ct < 4; ++ct) {
        float e = exp2f(sacc[ct][r] - m_run[r]);
        l_part[r] += e;
        Pw[w][prow][(ct * 16 + li) ^ ((prow & 7) << 3)] = __float2bfloat16(e);
      }
    }

    // drain this wave's P writes before reading them back (per-wave buffer)
    asm volatile("s_waitcnt lgkmcnt(0)" ::: "memory");
    __builtin_amdgcn_sched_barrier(0);

    // O += P V
#pragma unroll
    for (int ks = 0; ks < 2; ++ks) {
      short8 ap = *reinterpret_cast<const short8*>(
          &Pw[w][li][((ks * 4 + lg) ^ (li & 7)) * 8]);
#pragma unroll
      for (int dt = 0; dt < 8; ++dt) {
        short8 bv = *reinterpret_cast<const short8*>(
            &Vs[cur][dt * 16 + li][((ks * 4 + lg) ^ (li & 7)) * 8]);
        oacc[dt] = mfma_bf16(ap, bv, oacc[dt]);
      }
    }

    // own prefetch done + everyone finished reading `cur`
    asm volatile("s_waitcnt vmcnt(0)" ::: "memory");
    __syncthreads();
  }

  // epilogue: reduce the deferred denominator across the 16-lane row group
#pragma unroll
  for (int r = 0; r < 4; ++r) {
    float lsum = l_part[r];
    lsum += __shfl_xor(lsum, 1);
    lsum += __shfl_xor(lsum, 2);
    lsum += __shfl_xor(lsum, 4);
    lsum += __shfl_xor(lsum, 8);
    const float inv = 1.0f / lsum;
    const int t = qb0 + w * 16 + lg * 4 + r;
    bf16* op = O + (size_t)t * (NH * HD) + h * HD;
#pragma unroll
    for (int dt = 0; dt < 8; ++dt)
      op[dt * 16 + li] = __float2bfloat16(oacc[dt][r] * inv);
  }
}

// ---------------------------------------------------------------- launch

extern "C" void kernel_launch(void* const* d_in, const int* in_sizes, int n_in,
                              void* d_out, int out_size, void* d_ws, size_t ws_size,
                              hipStream_t stream) {
  const int* positions = (const int*)d_in[0];
  const float* hidden = (const float*)d_in[1];
  const float* w_qkv = (const float*)d_in[2];
  const float* b_qkv = (const float*)d_in[3];
  const float* w_o = (const float*)d_in[4];
  float* out = (float*)d_out;

  char* ws = (char*)d_ws;
  bf16* hs_bf = (bf16*)ws;   ws += (size_t)T_SEQ * HIDDEN * 2;
  bf16* wqkv_bf = (bf16*)ws; ws += (size_t)QKV_N * HIDDEN * 2;
  bf16* wo_bf = (bf16*)ws;   ws += (size_t)HIDDEN * HIDDEN * 2;
  float* qkv_f = (float*)ws; ws += (size_t)T_SEQ * QKV_N * 4;
  bf16* q_bf = (bf16*)ws;    ws += (size_t)NH * T_SEQ * HD * 2;
  bf16* k_bf = (bf16*)ws;    ws += (size_t)NKV * T_SEQ * HD * 2;
  bf16* vt_bf = (bf16*)ws;   ws += (size_t)NKV * T_SEQ * HD * 2;
  bf16* attn_bf = (bf16*)ws; ws += (size_t)T_SEQ * HIDDEN * 2;

  cvt_f32_bf16<<<(T_SEQ * HIDDEN) / 1024, 256, 0, stream>>>(hidden, hs_bf, T_SEQ * HIDDEN);
  cvt_f32_bf16<<<(QKV_N * HIDDEN) / 1024, 256, 0, stream>>>(w_qkv, wqkv_bf, QKV_N * HIDDEN);
  cvt_f32_bf16<<<(HIDDEN * HIDDEN) / 1024, 256, 0, stream>>>(w_o, wo_bf, HIDDEN * HIDDEN);

  gemm_bt<<<dim3(QKV_N / 128, T_SEQ / 128), 256, 0, stream>>>(hs_bf, wqkv_bf, qkv_f,
                                                              QKV_N, HIDDEN);

  rope_kernel<<<T_SEQ, 256, 0, stream>>>(qkv_f, b_qkv, positions, q_bf, k_bf, vt_bf);

  attn_kernel<<<dim3(T_SEQ / QB, NH), 256, 0, stream>>>(q_bf, k_bf, vt_bf, attn_bf);

  gemm_bt<<<dim3(HIDDEN / 128, T_SEQ / 128), 256, 0, stream>>>(attn_bf, wo_bf, out,
                                                               HIDDEN, HIDDEN);
}